// Round 13
// baseline (1019.903 us; speedup 1.0000x reference)
//
#include <hip/hip_runtime.h>
#include <hip/hip_bf16.h>

#define DEV __device__ __forceinline__

typedef unsigned short u16;
typedef __attribute__((ext_vector_type(8))) short bf16x8;
typedef __attribute__((ext_vector_type(4))) float f32x4;

static constexpr int MB_ = 2;
static constexpr int T_  = 1024;
static constexpr int H_  = 1024;
static constexpr int NH_ = 16;
static constexpr int L_  = 6;
static constexpr int V_  = 8192;
static constexpr int FF_ = 4096;
static constexpr int M_  = MB_ * T_;   // 2048 token rows
static constexpr int QKVN = 3 * H_;
static constexpr size_t GLDS = 98304;  // 96 KB dynamic LDS for gemm8

DEV u16 f2bf(float x) {
  __hip_bfloat16 h = __float2bfloat16(x);
  return *reinterpret_cast<u16*>(&h);
}
DEV float bf2f(u16 v) {
  unsigned u = (unsigned)v << 16;
  float f;
  __builtin_memcpy(&f, &u, 4);
  return f;
}

// ---------------- embedding + qkv-bias concat (fused) ----------------
__global__ __launch_bounds__(256) void embed_concat_kernel(
    const int* __restrict__ x, const float* __restrict__ tok,
    const float* __restrict__ pos, float* __restrict__ h, u16* __restrict__ hb,
    const float* __restrict__ bq, const float* __restrict__ bk,
    const float* __restrict__ bv, float* __restrict__ outb)
{
  int i = blockIdx.x;
  if (i < M_) {
    int t = threadIdx.x;
    int id = x[i];
    int tt = i & (T_ - 1);
    float4 a = *(const float4*)(tok + (size_t)id * H_ + t * 4);
    float4 b = *(const float4*)(pos + (size_t)tt * H_ + t * 4);
    float4 r = make_float4(a.x + b.x, a.y + b.y, a.z + b.z, a.w + b.w);
    *(float4*)(h + (size_t)i * H_ + t * 4) = r;
    ushort4 u = make_ushort4(f2bf(r.x), f2bf(r.y), f2bf(r.z), f2bf(r.w));
    *(ushort4*)(hb + (size_t)i * H_ + t * 4) = u;
  } else {
    int l = i - M_;
    for (int j = threadIdx.x; j < H_; j += 256) {
      outb[(size_t)l * QKVN + j]          = bq[(size_t)l * H_ + j];
      outb[(size_t)l * QKVN + H_ + j]     = bk[(size_t)l * H_ + j];
      outb[(size_t)l * QKVN + 2 * H_ + j] = bv[(size_t)l * H_ + j];
    }
  }
}

// ---------------- transpose helpers (128x128 per block via 64x64 LDS tile) ----
// Work guarded to threadIdx.x < 256 (callable from 512-thread kernels);
// __syncthreads() executed by ALL threads.
DEV void transpose_tile128s(float (*Ts)[65], const float* __restrict__ W,
                            u16* __restrict__ WT, int R, int C, int bx, int by)
{
  const int t = threadIdx.x;
  const bool act = t < 256;
  const int lr = (t & 255) >> 4;
  const int lcq = (t & 15) * 4;
  #pragma unroll
  for (int si = 0; si < 2; ++si) {
    #pragma unroll
    for (int sj = 0; sj < 2; ++sj) {
      const int r0 = by * 128 + si * 64, c0 = bx * 128 + sj * 64;
      if (act) {
        #pragma unroll
        for (int it = 0; it < 4; ++it) {
          int r = it * 16 + lr;
          float4 v = *(const float4*)(W + (size_t)(r0 + r) * C + c0 + lcq);
          Ts[r][lcq + 0] = v.x; Ts[r][lcq + 1] = v.y;
          Ts[r][lcq + 2] = v.z; Ts[r][lcq + 3] = v.w;
        }
      }
      __syncthreads();
      if (act) {
        #pragma unroll
        for (int it = 0; it < 4; ++it) {
          int n = it * 16 + lr;
          ushort4 u = make_ushort4(f2bf(Ts[lcq + 0][n]), f2bf(Ts[lcq + 1][n]),
                                   f2bf(Ts[lcq + 2][n]), f2bf(Ts[lcq + 3][n]));
          *(ushort4*)(WT + (size_t)(c0 + n) * R + r0 + lcq) = u;
        }
      }
      __syncthreads();
    }
  }
}

// 768 blocks: Wq,Wk,Wv,Wo (4x64) + W1 (256) + W2 (256)
DEV void transpose_layer_body(float (*Ts)[65], int t,
    const float* Wq, const float* Wk, const float* Wv, const float* Wo,
    const float* W1, const float* W2,
    u16* qkvT, u16* oT, u16* w1T, u16* w2T)
{
  if (t < 256) {
    int m = t >> 6, idx = t & 63, bx = idx & 7, by = idx >> 3;
    const float* W = (m == 0) ? Wq : (m == 1) ? Wk : (m == 2) ? Wv : Wo;
    u16* WT = (m == 3) ? oT : qkvT + (size_t)m * H_ * H_;
    transpose_tile128s(Ts, W, WT, H_, H_, bx, by);
  } else if (t < 512) {
    int idx = t - 256;
    transpose_tile128s(Ts, W1, w1T, H_, FF_, idx & 31, idx >> 5);
  } else {
    int idx = t - 512;
    transpose_tile128s(Ts, W2, w2T, FF_, H_, idx & 7, idx >> 3);
  }
}

__global__ __launch_bounds__(256) void transpose_layer_k(
    const float* __restrict__ Wq, const float* __restrict__ Wk,
    const float* __restrict__ Wv, const float* __restrict__ Wo,
    const float* __restrict__ W1, const float* __restrict__ W2,
    u16* qkvT, u16* oT, u16* w1T, u16* w2T)
{
  __shared__ float Ts[64][65];
  transpose_layer_body(Ts, blockIdx.x, Wq, Wk, Wv, Wo, W1, W2, qkvT, oT, w1T, w2T);
}

// ---------------- gemm8: 128x256 tile, 8 waves, r8 schedule ----------------
// BK=32, 4-buffer, counted vmcnt, STG-early. 2-row-packed conflict-free LDS
// layout (r8-verified, rows are 64B so it carries over unchanged).
// Staging: 3 wave-loads/step (A: rows [w*16,+16); B: [w*32,+16),[w*32+16,+16))
// -> steady vmcnt(6) = 2 future steps in flight. LDS: A 4x4096 u16, B 4x8192.

#define GLOAD_LDS16(g, l)                                              \
  __builtin_amdgcn_global_load_lds(                                    \
      (const __attribute__((address_space(1))) void*)(g),              \
      (__attribute__((address_space(3))) void*)(l), 16, 0, 0)

DEV void stage_rows16(const u16* __restrict__ G, int ldk, int r0g, int row0,
                      int kofs, u16* lds, int lane)
{
  const int rl = ((lane >> 3) << 1) | ((lane >> 2) & 1);  // logical row in 16-group
  const int row = row0 + rl;
  const int c = (lane & 3) ^ (((row0 >> 1) + (lane >> 3)) & 3);
  const u16* g = G + (size_t)(r0g + row) * ldk + kofs + c * 8;
  GLOAD_LDS16(g, lds + row0 * 32);          // wave-uniform base, lane*16B auto
}

DEV bf16x8 frag3(const u16* lds, int rr, int ch) {
  return *(const bf16x8*)(lds + (rr >> 1) * 64 + (rr & 1) * 32 +
                          ((ch ^ ((rr >> 1) & 3)) * 8));
}

template<int N>
DEV void wait_vm_barrier() {
  asm volatile("s_waitcnt vmcnt(%0)" :: "n"(N) : "memory");
  __builtin_amdgcn_s_barrier();
}

DEV void comp8(const u16* As, const u16* Bs, f32x4 (&acc)[4][4],
               int wm, int wn, int lc, int lg)
{
  bf16x8 af[4], bv[4];
  #pragma unroll
  for (int mi = 0; mi < 4; ++mi)
    af[mi] = frag3(As, wm * 64 + mi * 16 + lc, lg);
  #pragma unroll
  for (int ni = 0; ni < 4; ++ni)
    bv[ni] = frag3(Bs, wn * 64 + ni * 16 + lc, lg);
  #pragma unroll
  for (int mi = 0; mi < 4; ++mi)
    #pragma unroll
    for (int ni = 0; ni < 4; ++ni)
      acc[mi][ni] = __builtin_amdgcn_mfma_f32_16x16x32_bf16(af[mi], bv[ni], acc[mi][ni], 0, 0, 0);
}

template<bool PARTIAL, bool DO_GELU, bool WF, bool WB>
DEV void gemm8_body(u16* SMEM,
    const u16* __restrict__ A, const u16* __restrict__ BT,
    const float* __restrict__ bias, float* __restrict__ Cf,
    u16* __restrict__ Cb, u16* __restrict__ Pb,
    int N, int K, int Ksub, int lid, int nwgx, int nwgy, int zid)
{
  const int tid = threadIdx.x;
  const int lane = tid & 63, w = tid >> 6;     // 8 waves
  const int wm = w >> 2, wn = w & 3;           // 2M x 4N wave grid
  const int lc = lane & 15, lg = lane >> 4;

  // bijective XCD swizzle, m FASTEST within an XCD
  const int nwg = nwgx * nwgy;
  const int q8 = nwg >> 3, r8s = nwg & 7;
  const int xcd = lid & 7, ord = lid >> 3;
  const int sid = (xcd < r8s ? xcd * (q8 + 1) : r8s * (q8 + 1) + (xcd - r8s) * q8) + ord;
  const int m0 = (sid % nwgy) * 128, n0 = (sid / nwgy) * 256;

  const int kb = zid * Ksub;
  const int NT = Ksub >> 5;

  f32x4 acc[4][4];
  #pragma unroll
  for (int i = 0; i < 4; ++i)
    #pragma unroll
    for (int j = 0; j < 4; ++j) {
      f32x4 z = {0.f, 0.f, 0.f, 0.f};
      acc[i][j] = z;
    }

  auto STG = [&](int t, int b) {
    stage_rows16(A,  K, m0, w * 16,      kb + t * 32, SMEM + b * 4096, lane);
    stage_rows16(BT, K, n0, w * 32,      kb + t * 32, SMEM + 16384 + b * 8192, lane);
    stage_rows16(BT, K, n0, w * 32 + 16, kb + t * 32, SMEM + 16384 + b * 8192, lane);
  };

  STG(0, 0);
  STG(1, 1);
  int t = 0;
  for (; t < NT - 2; ++t) {
    STG(t + 2, (t + 2) & 3);
    wait_vm_barrier<6>();     // stage(t) complete; t+1,t+2 stay in flight
    comp8(SMEM + (t & 3) * 4096, SMEM + 16384 + (t & 3) * 8192, acc, wm, wn, lc, lg);
  }
  wait_vm_barrier<3>();       // stage(NT-2) complete
  comp8(SMEM + (t & 3) * 4096, SMEM + 16384 + (t & 3) * 8192, acc, wm, wn, lc, lg);
  ++t;
  wait_vm_barrier<0>();       // stage(NT-1) complete
  comp8(SMEM + (t & 3) * 4096, SMEM + 16384 + (t & 3) * 8192, acc, wm, wn, lc, lg);

  const size_t zofs = (size_t)zid * M_ * N;
  #pragma unroll
  for (int mi = 0; mi < 4; ++mi) {
    #pragma unroll
    for (int ni = 0; ni < 4; ++ni) {
      int gn = n0 + wn * 64 + ni * 16 + lc;
      float bvv = PARTIAL ? 0.f : bias[gn];
      #pragma unroll
      for (int r = 0; r < 4; ++r) {
        int gm = m0 + wm * 64 + mi * 16 + lg * 4 + r;
        float v = acc[mi][ni][r];
        if (PARTIAL) {
          Pb[zofs + (size_t)gm * N + gn] = f2bf(v);   // bf16 partials
        } else {
          v += bvv;
          if (DO_GELU) v = 0.5f * v * (1.f + erff(v * 0.70710678118654752f));
          if (WF) Cf[(size_t)gm * N + gn] = v;
          if (WB) Cb[(size_t)gm * N + gn] = f2bf(v);
        }
      }
    }
  }
}

template<bool PARTIAL, bool DO_GELU, bool WF, bool WB>
__global__ __launch_bounds__(512, 1) void gemm8(
    const u16* __restrict__ A, const u16* __restrict__ BT,
    const float* __restrict__ bias, float* __restrict__ Cf,
    u16* __restrict__ Cb, u16* __restrict__ Pb, int N, int K, int Ksub)
{
  extern __shared__ __align__(16) u16 SMEM[];
  gemm8_body<PARTIAL, DO_GELU, WF, WB>(SMEM, A, BT, bias, Cf, Cb, Pb, N, K, Ksub,
      blockIdx.y * gridDim.x + blockIdx.x, gridDim.x, gridDim.y, blockIdx.z);
}

// W1 GEMM (256 blocks) + next-layer weight transpose (768) or head transpose (512)
__global__ __launch_bounds__(512, 1) void gemmW1_fused(
    const u16* __restrict__ A, const u16* __restrict__ w1T,
    const float* __restrict__ bias, u16* __restrict__ m1,
    const float* nWq, const float* nWk, const float* nWv, const float* nWo,
    const float* nW1, const float* nW2,
    u16* nqkvT, u16* noT, u16* nw1T, u16* nw2T,
    const float* hW, u16* hT)
{
  extern __shared__ __align__(16) u16 SMEM[];
  const int id = blockIdx.x;
  if (id < 256) {
    gemm8_body<false, true, false, true>(SMEM, A, w1T, bias, nullptr, m1, nullptr,
                                         FF_, H_, H_, id, 16, 16, 0);
  } else if (nWq) {
    float (*Ts)[65] = (float(*)[65])SMEM;
    transpose_layer_body(Ts, id - 256, nWq, nWk, nWv, nWo, nW1, nW2,
                         nqkvT, noT, nw1T, nw2T);
  } else {
    float (*Ts)[65] = (float(*)[65])SMEM;
    int idx = id - 256;                     // 512 head tiles (64x8)
    transpose_tile128s(Ts, hW, hT, H_, V_, idx & 63, idx >> 6);
  }
}

// ---------------- split-K reduce (bf16 partials) + bias + residual + LN -------
__global__ __launch_bounds__(256) void ln2_kernel(
    const u16* __restrict__ Pb, int S,
    const float* __restrict__ bias,
    const float* __restrict__ g, const float* __restrict__ be,
    const float* __restrict__ gf, const float* __restrict__ bef,
    float* __restrict__ h, u16* __restrict__ hb)
{
  __shared__ float red[8];
  int row = blockIdx.x, t = threadIdx.x;
  int lane = t & 63, w = t >> 6;
  float4 v = *(const float4*)(h + (size_t)row * H_ + t * 4);
  float4 bb = *(const float4*)(bias + t * 4);
  v.x += bb.x; v.y += bb.y; v.z += bb.z; v.w += bb.w;
  for (int s0 = 0; s0 < S; ++s0) {
    ushort4 p = *(const ushort4*)(Pb + (size_t)s0 * M_ * H_ + (size_t)row * H_ + t * 4);
    v.x += bf2f(p.x); v.y += bf2f(p.y); v.z += bf2f(p.z); v.w += bf2f(p.w);
  }
  float s = v.x + v.y + v.z + v.w;
  float q = v.x * v.x + v.y * v.y + v.z * v.z + v.w * v.w;
  #pragma unroll
  for (int o = 1; o < 64; o <<= 1) { s += __shfl_xor(s, o); q += __shfl_xor(q, o); }
  if (lane == 0) { red[w] = s; red[4 + w] = q; }
  __syncthreads();
  float S1 = red[0] + red[1] + red[2] + red[3];
  float Q1 = red[4] + red[5] + red[6] + red[7];
  float mu  = S1 * (1.f / H_);
  float var = Q1 * (1.f / H_) - mu * mu;
  float inv = rsqrtf(var + 1e-5f);
  float4 gv = *(const float4*)(g  + t * 4);
  float4 bv = *(const float4*)(be + t * 4);
  float o0 = (v.x - mu) * inv * gv.x + bv.x;
  float o1 = (v.y - mu) * inv * gv.y + bv.y;
  float o2 = (v.z - mu) * inv * gv.z + bv.z;
  float o3 = (v.w - mu) * inv * gv.w + bv.w;
  if (gf == nullptr) {
    *(float4*)(h + (size_t)row * H_ + t * 4) = make_float4(o0, o1, o2, o3);
    ushort4 u = make_ushort4(f2bf(o0), f2bf(o1), f2bf(o2), f2bf(o3));
    *(ushort4*)(hb + (size_t)row * H_ + t * 4) = u;
  } else {
    float s2 = o0 + o1 + o2 + o3;
    float q2 = o0 * o0 + o1 * o1 + o2 * o2 + o3 * o3;
    #pragma unroll
    for (int o = 1; o < 64; o <<= 1) { s2 += __shfl_xor(s2, o); q2 += __shfl_xor(q2, o); }
    __syncthreads();
    if (lane == 0) { red[w] = s2; red[4 + w] = q2; }
    __syncthreads();
    float S2 = red[0] + red[1] + red[2] + red[3];
    float Q2 = red[4] + red[5] + red[6] + red[7];
    float mu2  = S2 * (1.f / H_);
    float var2 = Q2 * (1.f / H_) - mu2 * mu2;
    float inv2 = rsqrtf(var2 + 1e-5f);
    float4 gv2 = *(const float4*)(gf  + t * 4);
    float4 bv2 = *(const float4*)(bef + t * 4);
    ushort4 u = make_ushort4(f2bf((o0 - mu2) * inv2 * gv2.x + bv2.x),
                             f2bf((o1 - mu2) * inv2 * gv2.y + bv2.y),
                             f2bf((o2 - mu2) * inv2 * gv2.z + bv2.z),
                             f2bf((o3 - mu2) * inv2 * gv2.w + bv2.w));
    *(ushort4*)(hb + (size_t)row * H_ + t * 4) = u;
  }
}

// ---------------- flash attention (causal), D=64 ----------------
__global__ __launch_bounds__(256) void attn_kernel(
    const u16* __restrict__ qkv, u16* __restrict__ Og)
{
  __shared__ __align__(16) u16 Ks[2][64][72];
  __shared__ __align__(16) u16 Vs[2][64][72];      // transposed: [d][key]
  __shared__ __align__(16) u16 QPs[4][16][72];     // Q stage (prologue) / P bounce

  const int qb = gridDim.x - 1 - blockIdx.x;       // long blocks first
  const int bh = blockIdx.y;
  const int b = bh >> 4, hh = bh & 15;
  const int q0 = qb * 64;
  const size_t base  = ((size_t)b * T_) * QKVN + (size_t)hh * 64;
  const size_t baseO = ((size_t)b * T_) * H_ + (size_t)hh * 64;

  const int tid = threadIdx.x;
  const int lane = tid & 63, w = tid >> 6;
  const int lc = lane & 15, lg = lane >> 4;

  const int r8 = tid >> 3, d8 = (tid & 7) << 3;
  const int vk = tid & 31, vd = (tid >> 5) << 3;

  u16* Qflat = &QPs[0][0][0];

  bf16x8 kr[2], vr[2];
  #pragma unroll
  for (int i = 0; i < 2; ++i) {
    kr[i] = *(const bf16x8*)(qkv + base + H_ + (size_t)(i * 32 + r8) * QKVN + d8);
    vr[i] = *(const bf16x8*)(qkv + base + 2 * H_ + (size_t)(i * 32 + vk) * QKVN + vd);
  }
  #pragma unroll
  for (int i = 0; i < 2; ++i)
    *(bf16x8*)(Qflat + (size_t)(i * 32 + r8) * 72 + d8) =
      *(const bf16x8*)(qkv + base + (size_t)(q0 + i * 32 + r8) * QKVN + d8);
  #pragma unroll
  for (int i = 0; i < 2; ++i) {
    *(bf16x8*)&Ks[0][i * 32 + r8][d8] = kr[i];
    #pragma unroll
    for (int j = 0; j < 8; ++j) Vs[0][vd + j][i * 32 + vk] = ((const u16*)&vr[i])[j];
  }
  __syncthreads();
  bf16x8 aq0 = *(const bf16x8*)(Qflat + (size_t)(w * 16 + lc) * 72 + lg * 8);
  bf16x8 aq1 = *(const bf16x8*)(Qflat + (size_t)(w * 16 + lc) * 72 + 32 + lg * 8);

  float m_r[4], l_r[4];
  f32x4 oa[4];
  #pragma unroll
  for (int i = 0; i < 4; ++i) {
    m_r[i] = -1e30f; l_r[i] = 0.f;
    f32x4 z = {0.f, 0.f, 0.f, 0.f};
    oa[i] = z;
  }
  const float sc2 = 0.125f * 1.4426950408889634f;

  for (int kv = 0; kv <= qb; ++kv) {
    const int cur = kv & 1, nxt = cur ^ 1;
    if (kv < qb) {
      #pragma unroll
      for (int i = 0; i < 2; ++i) {
        kr[i] = *(const bf16x8*)(qkv + base + H_ + (size_t)((kv + 1) * 64 + i * 32 + r8) * QKVN + d8);
        vr[i] = *(const bf16x8*)(qkv + base + 2 * H_ + (size_t)((kv + 1) * 64 + i * 32 + vk) * QKVN + vd);
      }
    }

    f32x4 sfr[4];
    #pragma unroll
    for (int ni = 0; ni < 4; ++ni) { f32x4 z = {0.f,0.f,0.f,0.f}; sfr[ni] = z; }
    __builtin_amdgcn_s_setprio(1);
    #pragma unroll
    for (int ni = 0; ni < 4; ++ni) {
      bf16x8 bk0 = *(const bf16x8*)&Ks[cur][ni * 16 + lc][lg * 8];
      bf16x8 bk1 = *(const bf16x8*)&Ks[cur][ni * 16 + lc][32 + lg * 8];
      sfr[ni] = __builtin_amdgcn_mfma_f32_16x16x32_bf16(aq0, bk0, sfr[ni], 0, 0, 0);
      sfr[ni] = __builtin_amdgcn_mfma_f32_16x16x32_bf16(aq1, bk1, sfr[ni], 0, 0, 0);
    }
    __builtin_amdgcn_s_setprio(0);
    if (kv == qb) {
      #pragma unroll
      for (int ni = 0; ni < 4; ++ni)
        #pragma unroll
        for (int r = 0; r < 4; ++r)
          if (ni * 16 + lc > w * 16 + lg * 4 + r) sfr[ni][r] = -1e30f;
    }
    #pragma unroll
    for (int r = 0; r < 4; ++r) {
      float pm = fmaxf(fmaxf(sfr[0][r], sfr[1][r]), fmaxf(sfr[2][r], sfr[3][r]));
      pm = fmaxf(pm, __shfl_xor(pm, 1));
      pm = fmaxf(pm, __shfl_xor(pm, 2));
      pm = fmaxf(pm, __shfl_xor(pm, 4));
      pm = fmaxf(pm, __shfl_xor(pm, 8));
      float mn = fmaxf(m_r[r], pm);
      float al = exp2f(sc2 * (m_r[r] - mn));
      m_r[r] = mn; l_r[r] *= al;
      #pragma unroll
      for (int f = 0; f < 4; ++f) oa[f][r] *= al;
      float rs = 0.f;
      #pragma unroll
      for (int ni = 0; ni < 4; ++ni) {
        float p = exp2f(sc2 * (sfr[ni][r] - mn));
        sfr[ni][r] = p; rs += p;
      }
      rs += __shfl_xor(rs, 1); rs += __shfl_xor(rs, 2);
      rs += __shfl_xor(rs, 4); rs += __shfl_xor(rs, 8);
      l_r[r] += rs;
    }
    #pragma unroll
    for (int ni = 0; ni < 4; ++ni)
      #pragma unroll
      for (int r = 0; r < 4; ++r)
        QPs[w][lg * 4 + r][ni * 16 + lc] = f2bf(sfr[ni][r]);
    bf16x8 ap0 = *(const bf16x8*)&QPs[w][lc][lg * 8];
    bf16x8 ap1 = *(const bf16x8*)&QPs[w][lc][32 + lg * 8];
    __builtin_amdgcn_s_setprio(1);
    #pragma unroll
    for (int f = 0; f < 4; ++f) {
      bf16x8 bv0 = *(const bf16x8*)&Vs[cur][f * 16 + lc][lg * 8];
      bf16x8 bv1 = *(const bf16x8*)&Vs[cur][f * 16 + lc][32 + lg * 8];
      oa[f] = __builtin_amdgcn_mfma_f32_16x16x32_bf16(ap0, bv0, oa[f], 0, 0, 0);
      oa[f] = __builtin_amdgcn_mfma_f32_16x16x32_bf16(ap1, bv1, oa[f], 0, 0, 0);
    }
    __builtin_amdgcn_s_setprio(0);

    if (kv < qb) {
      #pragma unroll
      for (int i = 0; i < 2; ++i) {
        *(bf16x8*)&Ks[nxt][i * 32 + r8][d8] = kr[i];
        #pragma unroll
        for (int j = 0; j < 8; ++j) Vs[nxt][vd + j][i * 32 + vk] = ((const u16*)&vr[i])[j];
      }
      __syncthreads();
    }
  }

  #pragma unroll
  for (int r = 0; r < 4; ++r) {
    float inv = 1.f / l_r[r];
    int grow = q0 + w * 16 + lg * 4 + r;
    #pragma unroll
    for (int f = 0; f < 4; ++f)
      Og[baseO + (size_t)grow * H_ + f * 16 + lc] = f2bf(oa[f][r] * inv);
  }
}

// ---------------- host ----------------
extern "C" void kernel_launch(void* const* d_in, const int* in_sizes, int n_in,
                              void* d_out, int out_size, void* d_ws, size_t ws_size,
                              hipStream_t stream)
{
  const int*   x    = (const int*)  d_in[0];
  const float* tok  = (const float*)d_in[1];
  const float* pos  = (const float*)d_in[2];
  const float* Wq   = (const float*)d_in[3];
  const float* bq   = (const float*)d_in[4];
  const float* Wk   = (const float*)d_in[5];
  const float* bk   = (const float*)d_in[6];
  const float* Wv   = (const float*)d_in[7];
  const float* bv   = (const float*)d_in[8];
  const float* Wo   = (const float*)d_in[9];
  const float* bo   = (const float*)d_in[10];
  const float* W1   = (const float*)d_in[11];
  const float* b1   = (const float*)d_in[12];
  const float* W2   = (const float*)d_in[13];
  const float* b2   = (const float*)d_in[14];
  const float* g1   = (const float*)d_in[15];
  const float* be1  = (const float*)d_in[16];
  const float* g2   = (const float*)d_in[17];
  const float* be2  = (const float*)d_in[18];
  const float* gf   = (const float*)d_in[19];
  const float* bef  = (const float*)d_in[20];
  const float* hW   = (const float*)d_in[21];
  const float* hbias= (const float*)d_in[22];
  float* out = (float*)d_out;

  char* wsp = (char*)d_ws;
  size_t off = 0;
  auto alloc = [&](size_t bytes) -> void* {
    void* p = wsp + off;
    off += (bytes + 255) & ~(size_t)255;
    return p;
  };
  float* h    = (float*)alloc((size_t)M_ * H_ * 4);
  u16*   hb   = (u16*)  alloc((size_t)M_ * H_ * 2);
  u16*   qkv  = (u16*)  alloc((size_t)M_ * QKVN * 2);
  u16*   ob_  = (u16*)  alloc((size_t)M_ * H_ * 2);
  u16*   m1   = (u16*)  alloc((size_t)M_ * FF_ * 2);
  u16*   Pb   = (u16*)  alloc((size_t)4 * M_ * H_ * 2);   // bf16 split-K partials
  u16*   hT   = (u16*)  alloc((size_t)V_ * H_ * 2);
  u16*   qkvT = (u16*)  alloc((size_t)QKVN * H_ * 2);
  u16*   oT   = (u16*)  alloc((size_t)H_ * H_ * 2);
  u16*   w1Tb = (u16*)  alloc((size_t)2 * H_ * FF_ * 2);  // double-buffered
  u16*   w2Tb = (u16*)  alloc((size_t)2 * FF_ * H_ * 2);  // double-buffered
  float* bqkv = (float*)alloc((size_t)L_ * QKVN * 4);
  (void)in_sizes; (void)n_in; (void)out_size; (void)ws_size;

  auto w1T = [&](int l) { return w1Tb + (size_t)(l & 1) * H_ * FF_; };
  auto w2T = [&](int l) { return w2Tb + (size_t)(l & 1) * FF_ * H_; };

  embed_concat_kernel<<<M_ + L_, 256, 0, stream>>>(x, tok, pos, h, hb,
                                                   bq, bk, bv, bqkv);
  // layer-0 weights: standalone transpose
  transpose_layer_k<<<768, 256, 0, stream>>>(
      Wq, Wk, Wv, Wo, W1, W2, qkvT, oT, w1T(0), w2T(0));

  for (int l = 0; l < L_; ++l) {
    // QKV: [2048,3072], grid 12x16
    gemm8<false, false, false, true><<<dim3(QKVN / 256, M_ / 128, 1), 512, GLDS, stream>>>(
        hb, qkvT, bqkv + (size_t)l * QKVN, nullptr, qkv, nullptr, QKVN, H_, H_);
    attn_kernel<<<dim3(T_ / 64, MB_ * NH_), 256, 0, stream>>>(qkv, ob_);
    // O-proj: split-K x4, grid 4x16x4 = 256
    gemm8<true, false, false, false><<<dim3(H_ / 256, M_ / 128, 4), 512, GLDS, stream>>>(
        ob_, oT, nullptr, nullptr, nullptr, Pb, H_, H_, H_ / 4);
    ln2_kernel<<<M_, 256, 0, stream>>>(Pb, 4, bo + l * H_, g1 + l * H_, be1 + l * H_,
                                       nullptr, nullptr, h, hb);
    // W1 + GELU (256 blocks), fused with next-layer (or head) transpose
    if (l + 1 < L_) {
      int nl = l + 1;
      gemmW1_fused<<<256 + 768, 512, GLDS, stream>>>(
          hb, w1T(l), b1 + (size_t)l * FF_, m1,
          Wq + (size_t)nl * H_ * H_, Wk + (size_t)nl * H_ * H_,
          Wv + (size_t)nl * H_ * H_, Wo + (size_t)nl * H_ * H_,
          W1 + (size_t)nl * H_ * FF_, W2 + (size_t)nl * FF_ * H_,
          qkvT, oT, w1T(nl), w2T(nl), nullptr, nullptr);
    } else {
      gemmW1_fused<<<256 + 512, 512, GLDS, stream>>>(
          hb, w1T(l), b1 + (size_t)l * FF_, m1,
          nullptr, nullptr, nullptr, nullptr, nullptr, nullptr,
          nullptr, nullptr, nullptr, nullptr, hW, hT);
    }
    // W2: split-K x4, grid 4x16x4 = 256
    gemm8<true, false, false, false><<<dim3(H_ / 256, M_ / 128, 4), 512, GLDS, stream>>>(
        m1, w2T(l), nullptr, nullptr, nullptr, Pb, H_, FF_, FF_ / 4);
    if (l + 1 < L_) {
      ln2_kernel<<<M_, 256, 0, stream>>>(Pb, 4, b2 + l * H_, g2 + l * H_, be2 + l * H_,
                                         nullptr, nullptr, h, hb);
    } else {
      ln2_kernel<<<M_, 256, 0, stream>>>(Pb, 4, b2 + l * H_, g2 + l * H_, be2 + l * H_,
                                         gf, bef, h, hb);
    }
  }

  // head: [2048,8192], grid 32x16
  gemm8<false, false, true, false><<<dim3(V_ / 256, M_ / 128, 1), 512, GLDS, stream>>>(
      hb, hT, hbias, out, nullptr, nullptr, V_, H_, H_);
}

// Round 14
// 994.900 us; speedup vs baseline: 1.0251x; 1.0251x over previous
//
#include <hip/hip_runtime.h>
#include <hip/hip_bf16.h>

#define DEV __device__ __forceinline__

typedef unsigned short u16;
typedef __attribute__((ext_vector_type(8))) short bf16x8;
typedef __attribute__((ext_vector_type(4))) float f32x4;

static constexpr int MB_ = 2;
static constexpr int T_  = 1024;
static constexpr int H_  = 1024;
static constexpr int NH_ = 16;
static constexpr int L_  = 6;
static constexpr int V_  = 8192;
static constexpr int FF_ = 4096;
static constexpr int M_  = MB_ * T_;   // 2048 token rows
static constexpr int QKVN = 3 * H_;

DEV u16 f2bf(float x) {
  __hip_bfloat16 h = __float2bfloat16(x);
  return *reinterpret_cast<u16*>(&h);
}
DEV float bf2f(u16 v) {
  unsigned u = (unsigned)v << 16;
  float f;
  __builtin_memcpy(&f, &u, 4);
  return f;
}

// ---------------- embedding + qkv-bias concat (fused) ----------------
__global__ __launch_bounds__(256) void embed_concat_kernel(
    const int* __restrict__ x, const float* __restrict__ tok,
    const float* __restrict__ pos, float* __restrict__ h, u16* __restrict__ hb,
    const float* __restrict__ bq, const float* __restrict__ bk,
    const float* __restrict__ bv, float* __restrict__ outb)
{
  int i = blockIdx.x;
  if (i < M_) {
    int t = threadIdx.x;
    int id = x[i];
    int tt = i & (T_ - 1);
    float4 a = *(const float4*)(tok + (size_t)id * H_ + t * 4);
    float4 b = *(const float4*)(pos + (size_t)tt * H_ + t * 4);
    float4 r = make_float4(a.x + b.x, a.y + b.y, a.z + b.z, a.w + b.w);
    *(float4*)(h + (size_t)i * H_ + t * 4) = r;
    ushort4 u = make_ushort4(f2bf(r.x), f2bf(r.y), f2bf(r.z), f2bf(r.w));
    *(ushort4*)(hb + (size_t)i * H_ + t * 4) = u;
  } else {
    int l = i - M_;
    for (int j = threadIdx.x; j < H_; j += 256) {
      outb[(size_t)l * QKVN + j]          = bq[(size_t)l * H_ + j];
      outb[(size_t)l * QKVN + H_ + j]     = bk[(size_t)l * H_ + j];
      outb[(size_t)l * QKVN + 2 * H_ + j] = bv[(size_t)l * H_ + j];
    }
  }
}

// ---------------- transpose helpers (128x128 per block via 64x64 LDS tile) ----
DEV void transpose_tile128s(float (*Ts)[65], const float* __restrict__ W,
                            u16* __restrict__ WT, int R, int C, int bx, int by)
{
  const int t = threadIdx.x;
  const int lr = t >> 4;
  const int lcq = (t & 15) * 4;
  #pragma unroll
  for (int si = 0; si < 2; ++si) {
    #pragma unroll
    for (int sj = 0; sj < 2; ++sj) {
      const int r0 = by * 128 + si * 64, c0 = bx * 128 + sj * 64;
      #pragma unroll
      for (int it = 0; it < 4; ++it) {
        int r = it * 16 + lr;
        float4 v = *(const float4*)(W + (size_t)(r0 + r) * C + c0 + lcq);
        Ts[r][lcq + 0] = v.x; Ts[r][lcq + 1] = v.y;
        Ts[r][lcq + 2] = v.z; Ts[r][lcq + 3] = v.w;
      }
      __syncthreads();
      #pragma unroll
      for (int it = 0; it < 4; ++it) {
        int n = it * 16 + lr;
        ushort4 u = make_ushort4(f2bf(Ts[lcq + 0][n]), f2bf(Ts[lcq + 1][n]),
                                 f2bf(Ts[lcq + 2][n]), f2bf(Ts[lcq + 3][n]));
        *(ushort4*)(WT + (size_t)(c0 + n) * R + r0 + lcq) = u;
      }
      __syncthreads();
    }
  }
}

// 768 blocks: Wq,Wk,Wv,Wo (4x64) + W1 (256) + W2 (256)
DEV void transpose_layer_body(float (*Ts)[65], int t,
    const float* Wq, const float* Wk, const float* Wv, const float* Wo,
    const float* W1, const float* W2,
    u16* qkvT, u16* oT, u16* w1T, u16* w2T)
{
  if (t < 256) {
    int m = t >> 6, idx = t & 63, bx = idx & 7, by = idx >> 3;
    const float* W = (m == 0) ? Wq : (m == 1) ? Wk : (m == 2) ? Wv : Wo;
    u16* WT = (m == 3) ? oT : qkvT + (size_t)m * H_ * H_;
    transpose_tile128s(Ts, W, WT, H_, H_, bx, by);
  } else if (t < 512) {
    int idx = t - 256;
    transpose_tile128s(Ts, W1, w1T, H_, FF_, idx & 31, idx >> 5);
  } else {
    int idx = t - 512;
    transpose_tile128s(Ts, W2, w2T, FF_, H_, idx & 7, idx >> 3);
  }
}

__global__ __launch_bounds__(256) void transpose_layer_k(
    const float* __restrict__ Wq, const float* __restrict__ Wk,
    const float* __restrict__ Wv, const float* __restrict__ Wo,
    const float* __restrict__ W1, const float* __restrict__ W2,
    u16* qkvT, u16* oT, u16* w1T, u16* w2T)
{
  __shared__ float Ts[64][65];
  transpose_layer_body(Ts, blockIdx.x, Wq, Wk, Wv, Wo, W1, W2, qkvT, oT, w1T, w2T);
}

// ---------------- pipelined GEMM body (r8/r12-exact schedule) ----------------
// 4-buffer, BK=32, counted vmcnt, STG-early, 2 blocks/CU.
// 2-row-packed conflict-free LDS layout (r8-verified: SQ_LDS_BANK_CONFLICT=0).

#define GLOAD_LDS16(g, l)                                              \
  __builtin_amdgcn_global_load_lds(                                    \
      (const __attribute__((address_space(1))) void*)(g),              \
      (__attribute__((address_space(3))) void*)(l), 16, 0, 0)

DEV void stage_t(const u16* __restrict__ G, int ldk, int r0g, int kofs,
                 u16* lds, int w, int lane)
{
  const int rl = ((lane >> 3) << 1) | ((lane >> 2) & 1);  // logical row in 16-group
  #pragma unroll
  for (int j = 0; j < 2; ++j) {
    const int row0 = w * 32 + j * 16;
    const int row = row0 + rl;
    const int c = (lane & 3) ^ (((row0 >> 1) + (lane >> 3)) & 3);
    const u16* g = G + (size_t)(r0g + row) * ldk + kofs + c * 8;
    GLOAD_LDS16(g, lds + row0 * 32);        // wave-uniform base, lane*16B auto
  }
}

DEV bf16x8 frag3(const u16* lds, int rr, int ch) {
  return *(const bf16x8*)(lds + (rr >> 1) * 64 + (rr & 1) * 32 +
                          ((ch ^ ((rr >> 1) & 3)) * 8));
}

template<int N>
DEV void wait_vm_barrier() {
  asm volatile("s_waitcnt vmcnt(%0)" :: "n"(N) : "memory");
  __builtin_amdgcn_s_barrier();
}

DEV void comp3(const u16* As, const u16* Bs, f32x4 (&acc)[4][4],
               int wr, int wc, int lc, int lg)
{
  bf16x8 af[4], bv[4];
  #pragma unroll
  for (int mi = 0; mi < 4; ++mi)
    af[mi] = frag3(As, wr * 64 + mi * 16 + lc, lg);
  #pragma unroll
  for (int ni = 0; ni < 4; ++ni)
    bv[ni] = frag3(Bs, wc * 64 + ni * 16 + lc, lg);
  #pragma unroll
  for (int mi = 0; mi < 4; ++mi)
    #pragma unroll
    for (int ni = 0; ni < 4; ++ni)
      acc[mi][ni] = __builtin_amdgcn_mfma_f32_16x16x32_bf16(af[mi], bv[ni], acc[mi][ni], 0, 0, 0);
}

template<bool PARTIAL, bool DO_GELU, bool WF, bool WB>
DEV void gemm_body(u16* SMEM,
    const u16* __restrict__ A, const u16* __restrict__ BT,
    const float* __restrict__ bias, float* __restrict__ Cf,
    u16* __restrict__ Cb, u16* __restrict__ Pb,
    int N, int K, int Ksub, int lid, int nwgx, int nwgy, int zid)
{
  const int tid = threadIdx.x;
  const int lane = tid & 63, w = tid >> 6;
  const int wr = w >> 1, wc = w & 1;
  const int lc = lane & 15, lg = lane >> 4;

  // bijective XCD swizzle, m FASTEST within an XCD (B-panel reuse per XCD)
  const int nwg = nwgx * nwgy;
  const int q8 = nwg >> 3, r8s = nwg & 7;
  const int xcd = lid & 7, ord = lid >> 3;
  const int sid = (xcd < r8s ? xcd * (q8 + 1) : r8s * (q8 + 1) + (xcd - r8s) * q8) + ord;
  const int m0 = (sid % nwgy) * 128, n0 = (sid / nwgy) * 128;

  const int kb = zid * Ksub;
  const int NT = Ksub >> 5;

  f32x4 acc[4][4];
  #pragma unroll
  for (int i = 0; i < 4; ++i)
    #pragma unroll
    for (int j = 0; j < 4; ++j) {
      f32x4 z = {0.f, 0.f, 0.f, 0.f};
      acc[i][j] = z;
    }

  auto STG = [&](int t, int b) {
    stage_t(A,  K, m0, kb + t * 32, SMEM + b * 4096, w, lane);
    stage_t(BT, K, n0, kb + t * 32, SMEM + 16384 + b * 4096, w, lane);
  };

  STG(0, 0);
  STG(1, 1);
  int t = 0;
  for (; t < NT - 2; ++t) {
    STG(t + 2, (t + 2) & 3);
    wait_vm_barrier<8>();     // stage(t) complete; t+1,t+2 stay in flight
    comp3(SMEM + (t & 3) * 4096, SMEM + 16384 + (t & 3) * 4096, acc, wr, wc, lc, lg);
  }
  wait_vm_barrier<4>();       // stage(NT-2) complete
  comp3(SMEM + (t & 3) * 4096, SMEM + 16384 + (t & 3) * 4096, acc, wr, wc, lc, lg);
  ++t;
  wait_vm_barrier<0>();       // stage(NT-1) complete
  comp3(SMEM + (t & 3) * 4096, SMEM + 16384 + (t & 3) * 4096, acc, wr, wc, lc, lg);

  const size_t zofs = (size_t)zid * M_ * N;
  #pragma unroll
  for (int mi = 0; mi < 4; ++mi) {
    #pragma unroll
    for (int ni = 0; ni < 4; ++ni) {
      int gn = n0 + wc * 64 + ni * 16 + lc;
      float bvv = PARTIAL ? 0.f : bias[gn];
      #pragma unroll
      for (int r = 0; r < 4; ++r) {
        int gm = m0 + wr * 64 + mi * 16 + lg * 4 + r;
        float v = acc[mi][ni][r];
        if (PARTIAL) {
          Pb[zofs + (size_t)gm * N + gn] = f2bf(v);   // bf16 partials
        } else {
          v += bvv;
          if (DO_GELU) v = 0.5f * v * (1.f + erff(v * 0.70710678118654752f));
          if (WF) Cf[(size_t)gm * N + gn] = v;
          if (WB) Cb[(size_t)gm * N + gn] = f2bf(v);
        }
      }
    }
  }
}

template<bool PARTIAL, bool DO_GELU, bool WF, bool WB>
__global__ __launch_bounds__(256, 2) void gemm3(
    const u16* __restrict__ A, const u16* __restrict__ BT,
    const float* __restrict__ bias, float* __restrict__ Cf,
    u16* __restrict__ Cb, u16* __restrict__ Pb, int N, int K, int Ksub)
{
  __shared__ __align__(16) u16 SMEM[32768];
  gemm_body<PARTIAL, DO_GELU, WF, WB>(SMEM, A, BT, bias, Cf, Cb, Pb, N, K, Ksub,
      blockIdx.y * gridDim.x + blockIdx.x, gridDim.x, gridDim.y, blockIdx.z);
}

// W1 GEMM (512 blocks) + next-layer weight transpose (768) or head transpose (512)
__global__ __launch_bounds__(256, 2) void gemmW1_fused(
    const u16* __restrict__ A, const u16* __restrict__ w1T,
    const float* __restrict__ bias, u16* __restrict__ m1,
    const float* nWq, const float* nWk, const float* nWv, const float* nWo,
    const float* nW1, const float* nW2,
    u16* nqkvT, u16* noT, u16* nw1T, u16* nw2T,
    const float* hW, u16* hT)
{
  __shared__ __align__(16) u16 SMEM[32768];
  const int id = blockIdx.x;
  if (id < 512) {
    gemm_body<false, true, false, true>(SMEM, A, w1T, bias, nullptr, m1, nullptr,
                                        FF_, H_, H_, id, 32, 16, 0);
  } else if (nWq) {
    float (*Ts)[65] = (float(*)[65])SMEM;
    transpose_layer_body(Ts, id - 512, nWq, nWk, nWv, nWo, nW1, nW2,
                         nqkvT, noT, nw1T, nw2T);
  } else {
    float (*Ts)[65] = (float(*)[65])SMEM;
    int idx = id - 512;                     // 512 head tiles (64x8)
    transpose_tile128s(Ts, hW, hT, H_, V_, idx & 63, idx >> 6);
  }
}

// ---------------- split-K reduce (bf16 partials) + bias + residual + LN -------
__global__ __launch_bounds__(256) void ln2_kernel(
    const u16* __restrict__ Pb, int S,
    const float* __restrict__ bias,
    const float* __restrict__ g, const float* __restrict__ be,
    const float* __restrict__ gf, const float* __restrict__ bef,
    float* __restrict__ h, u16* __restrict__ hb)
{
  __shared__ float red[8];
  int row = blockIdx.x, t = threadIdx.x;
  int lane = t & 63, w = t >> 6;
  float4 v = *(const float4*)(h + (size_t)row * H_ + t * 4);
  float4 bb = *(const float4*)(bias + t * 4);
  v.x += bb.x; v.y += bb.y; v.z += bb.z; v.w += bb.w;
  for (int s0 = 0; s0 < S; ++s0) {
    ushort4 p = *(const ushort4*)(Pb + (size_t)s0 * M_ * H_ + (size_t)row * H_ + t * 4);
    v.x += bf2f(p.x); v.y += bf2f(p.y); v.z += bf2f(p.z); v.w += bf2f(p.w);
  }
  float s = v.x + v.y + v.z + v.w;
  float q = v.x * v.x + v.y * v.y + v.z * v.z + v.w * v.w;
  #pragma unroll
  for (int o = 1; o < 64; o <<= 1) { s += __shfl_xor(s, o); q += __shfl_xor(q, o); }
  if (lane == 0) { red[w] = s; red[4 + w] = q; }
  __syncthreads();
  float S1 = red[0] + red[1] + red[2] + red[3];
  float Q1 = red[4] + red[5] + red[6] + red[7];
  float mu  = S1 * (1.f / H_);
  float var = Q1 * (1.f / H_) - mu * mu;
  float inv = rsqrtf(var + 1e-5f);
  float4 gv = *(const float4*)(g  + t * 4);
  float4 bv = *(const float4*)(be + t * 4);
  float o0 = (v.x - mu) * inv * gv.x + bv.x;
  float o1 = (v.y - mu) * inv * gv.y + bv.y;
  float o2 = (v.z - mu) * inv * gv.z + bv.z;
  float o3 = (v.w - mu) * inv * gv.w + bv.w;
  if (gf == nullptr) {
    *(float4*)(h + (size_t)row * H_ + t * 4) = make_float4(o0, o1, o2, o3);
    ushort4 u = make_ushort4(f2bf(o0), f2bf(o1), f2bf(o2), f2bf(o3));
    *(ushort4*)(hb + (size_t)row * H_ + t * 4) = u;
  } else {
    float s2 = o0 + o1 + o2 + o3;
    float q2 = o0 * o0 + o1 * o1 + o2 * o2 + o3 * o3;
    #pragma unroll
    for (int o = 1; o < 64; o <<= 1) { s2 += __shfl_xor(s2, o); q2 += __shfl_xor(q2, o); }
    __syncthreads();
    if (lane == 0) { red[w] = s2; red[4 + w] = q2; }
    __syncthreads();
    float S2 = red[0] + red[1] + red[2] + red[3];
    float Q2 = red[4] + red[5] + red[6] + red[7];
    float mu2  = S2 * (1.f / H_);
    float var2 = Q2 * (1.f / H_) - mu2 * mu2;
    float inv2 = rsqrtf(var2 + 1e-5f);
    float4 gv2 = *(const float4*)(gf  + t * 4);
    float4 bv2 = *(const float4*)(bef + t * 4);
    ushort4 u = make_ushort4(f2bf((o0 - mu2) * inv2 * gv2.x + bv2.x),
                             f2bf((o1 - mu2) * inv2 * gv2.y + bv2.y),
                             f2bf((o2 - mu2) * inv2 * gv2.z + bv2.z),
                             f2bf((o3 - mu2) * inv2 * gv2.w + bv2.w));
    *(ushort4*)(hb + (size_t)row * H_ + t * 4) = u;
  }
}

// ---------------- flash attention (causal), QBLK=128, 8 waves ----------------
// K/V tiles (64 keys) shared by 8 waves (each wave owns 16 q-rows) -> K/V
// traffic halved vs QBLK=64. Per-wave math identical to r12. Double-buffered
// K/V, one barrier per kv-iter. Q staged through the per-wave P-bounce slice.
__global__ __launch_bounds__(512) void attn_kernel(
    const u16* __restrict__ qkv, u16* __restrict__ Og)
{
  __shared__ __align__(16) u16 Ks[2][64][72];
  __shared__ __align__(16) u16 Vs[2][64][72];      // transposed: [d][key]
  __shared__ __align__(16) u16 QPs[8][16][72];     // Q stage (prologue) / P bounce

  const int qb = gridDim.x - 1 - blockIdx.x;       // long blocks first
  const int bh = blockIdx.y;
  const int b = bh >> 4, hh = bh & 15;
  const int q0 = qb * 128;
  const size_t base  = ((size_t)b * T_) * QKVN + (size_t)hh * 64;
  const size_t baseO = ((size_t)b * T_) * H_ + (size_t)hh * 64;

  const int tid = threadIdx.x;
  const int lane = tid & 63, w = tid >> 6;         // 8 waves
  const int lc = lane & 15, lg = lane >> 4;

  const int rk = tid >> 3, dk = (tid & 7) << 3;    // K: 64 rows x 8 chunks
  const int vk = tid & 63, vd = (tid >> 6) << 3;   // V: 64 rows x 8 d-chunks
  const int rq = tid >> 2, cq = (tid & 3) << 4;    // Q: 128 rows x 2 chunks

  // ---- prologue: load Q, K0, V0 ----
  bf16x8 kr, vr;
  kr = *(const bf16x8*)(qkv + base + H_ + (size_t)rk * QKVN + dk);
  vr = *(const bf16x8*)(qkv + base + 2 * H_ + (size_t)vk * QKVN + vd);
  *(bf16x8*)&QPs[rq >> 4][rq & 15][cq] =
      *(const bf16x8*)(qkv + base + (size_t)(q0 + rq) * QKVN + cq);
  *(bf16x8*)&QPs[rq >> 4][rq & 15][cq + 8] =
      *(const bf16x8*)(qkv + base + (size_t)(q0 + rq) * QKVN + cq + 8);
  *(bf16x8*)&Ks[0][rk][dk] = kr;
  #pragma unroll
  for (int j = 0; j < 8; ++j) Vs[0][vd + j][vk] = ((const u16*)&vr)[j];
  __syncthreads();
  bf16x8 aq0 = *(const bf16x8*)&QPs[w][lc][lg * 8];
  bf16x8 aq1 = *(const bf16x8*)&QPs[w][lc][32 + lg * 8];

  float m_r[4], l_r[4];
  f32x4 oa[4];
  #pragma unroll
  for (int i = 0; i < 4; ++i) {
    m_r[i] = -1e30f; l_r[i] = 0.f;
    f32x4 z = {0.f, 0.f, 0.f, 0.f};
    oa[i] = z;
  }
  const float sc2 = 0.125f * 1.4426950408889634f;
  const int NT = 2 * qb + 2;
  const int rmin = q0 + w * 16;                    // wave's first q-row

  for (int kv = 0; kv < NT; ++kv) {
    const int cur = kv & 1, nxt = cur ^ 1;
    if (kv + 1 < NT) {
      kr = *(const bf16x8*)(qkv + base + H_ + (size_t)((kv + 1) * 64 + rk) * QKVN + dk);
      vr = *(const bf16x8*)(qkv + base + 2 * H_ + (size_t)((kv + 1) * 64 + vk) * QKVN + vd);
    }

    const bool live = (kv * 64 <= rmin + 15);      // else tile fully masked
    if (live) {
      const bool partial = (kv * 64 + 63 > rmin);
      f32x4 sfr[4];
      #pragma unroll
      for (int ni = 0; ni < 4; ++ni) { f32x4 z = {0.f,0.f,0.f,0.f}; sfr[ni] = z; }
      __builtin_amdgcn_s_setprio(1);
      #pragma unroll
      for (int ni = 0; ni < 4; ++ni) {
        bf16x8 bk0 = *(const bf16x8*)&Ks[cur][ni * 16 + lc][lg * 8];
        bf16x8 bk1 = *(const bf16x8*)&Ks[cur][ni * 16 + lc][32 + lg * 8];
        sfr[ni] = __builtin_amdgcn_mfma_f32_16x16x32_bf16(aq0, bk0, sfr[ni], 0, 0, 0);
        sfr[ni] = __builtin_amdgcn_mfma_f32_16x16x32_bf16(aq1, bk1, sfr[ni], 0, 0, 0);
      }
      __builtin_amdgcn_s_setprio(0);
      if (partial) {
        #pragma unroll
        for (int ni = 0; ni < 4; ++ni)
          #pragma unroll
          for (int r = 0; r < 4; ++r)
            if (kv * 64 + ni * 16 + lc > rmin + lg * 4 + r) sfr[ni][r] = -1e30f;
      }
      #pragma unroll
      for (int r = 0; r < 4; ++r) {
        float pm = fmaxf(fmaxf(sfr[0][r], sfr[1][r]), fmaxf(sfr[2][r], sfr[3][r]));
        pm = fmaxf(pm, __shfl_xor(pm, 1));
        pm = fmaxf(pm, __shfl_xor(pm, 2));
        pm = fmaxf(pm, __shfl_xor(pm, 4));
        pm = fmaxf(pm, __shfl_xor(pm, 8));
        float mn = fmaxf(m_r[r], pm);
        float al = exp2f(sc2 * (m_r[r] - mn));
        m_r[r] = mn; l_r[r] *= al;
        #pragma unroll
        for (int f = 0; f < 4; ++f) oa[f][r] *= al;
        float rs = 0.f;
        #pragma unroll
        for (int ni = 0; ni < 4; ++ni) {
          float p = exp2f(sc2 * (sfr[ni][r] - mn));
          sfr[ni][r] = p; rs += p;
        }
        rs += __shfl_xor(rs, 1); rs += __shfl_xor(rs, 2);
        rs += __shfl_xor(rs, 4); rs += __shfl_xor(rs, 8);
        l_r[r] += rs;
      }
      #pragma unroll
      for (int ni = 0; ni < 4; ++ni)
        #pragma unroll
        for (int r = 0; r < 4; ++r)
          QPs[w][lg * 4 + r][ni * 16 + lc] = f2bf(sfr[ni][r]);
      bf16x8 ap0 = *(const bf16x8*)&QPs[w][lc][lg * 8];
      bf16x8 ap1 = *(const bf16x8*)&QPs[w][lc][32 + lg * 8];
      __builtin_amdgcn_s_setprio(1);
      #pragma unroll
      for (int f = 0; f < 4; ++f) {
        bf16x8 bv0 = *(const bf16x8*)&Vs[cur][f * 16 + lc][lg * 8];
        bf16x8 bv1 = *(const bf16x8*)&Vs[cur][f * 16 + lc][32 + lg * 8];
        oa[f] = __builtin_amdgcn_mfma_f32_16x16x32_bf16(ap0, bv0, oa[f], 0, 0, 0);
        oa[f] = __builtin_amdgcn_mfma_f32_16x16x32_bf16(ap1, bv1, oa[f], 0, 0, 0);
      }
      __builtin_amdgcn_s_setprio(0);
    }

    if (kv + 1 < NT) {
      *(bf16x8*)&Ks[nxt][rk][dk] = kr;
      #pragma unroll
      for (int j = 0; j < 8; ++j) Vs[nxt][vd + j][vk] = ((const u16*)&vr)[j];
      __syncthreads();
    }
  }

  #pragma unroll
  for (int r = 0; r < 4; ++r) {
    float inv = 1.f / l_r[r];
    int grow = q0 + w * 16 + lg * 4 + r;
    #pragma unroll
    for (int f = 0; f < 4; ++f)
      Og[baseO + (size_t)grow * H_ + f * 16 + lc] = f2bf(oa[f][r] * inv);
  }
}

// ---------------- host ----------------
extern "C" void kernel_launch(void* const* d_in, const int* in_sizes, int n_in,
                              void* d_out, int out_size, void* d_ws, size_t ws_size,
                              hipStream_t stream)
{
  const int*   x    = (const int*)  d_in[0];
  const float* tok  = (const float*)d_in[1];
  const float* pos  = (const float*)d_in[2];
  const float* Wq   = (const float*)d_in[3];
  const float* bq   = (const float*)d_in[4];
  const float* Wk   = (const float*)d_in[5];
  const float* bk   = (const float*)d_in[6];
  const float* Wv   = (const float*)d_in[7];
  const float* bv   = (const float*)d_in[8];
  const float* Wo   = (const float*)d_in[9];
  const float* bo   = (const float*)d_in[10];
  const float* W1   = (const float*)d_in[11];
  const float* b1   = (const float*)d_in[12];
  const float* W2   = (const float*)d_in[13];
  const float* b2   = (const float*)d_in[14];
  const float* g1   = (const float*)d_in[15];
  const float* be1  = (const float*)d_in[16];
  const float* g2   = (const float*)d_in[17];
  const float* be2  = (const float*)d_in[18];
  const float* gf   = (const float*)d_in[19];
  const float* bef  = (const float*)d_in[20];
  const float* hW   = (const float*)d_in[21];
  const float* hbias= (const float*)d_in[22];
  float* out = (float*)d_out;

  char* wsp = (char*)d_ws;
  size_t off = 0;
  auto alloc = [&](size_t bytes) -> void* {
    void* p = wsp + off;
    off += (bytes + 255) & ~(size_t)255;
    return p;
  };
  float* h    = (float*)alloc((size_t)M_ * H_ * 4);
  u16*   hb   = (u16*)  alloc((size_t)M_ * H_ * 2);
  u16*   qkv  = (u16*)  alloc((size_t)M_ * QKVN * 2);
  u16*   ob_  = (u16*)  alloc((size_t)M_ * H_ * 2);
  u16*   m1   = (u16*)  alloc((size_t)M_ * FF_ * 2);
  u16*   Pb   = (u16*)  alloc((size_t)4 * M_ * H_ * 2);   // bf16 split-K partials
  u16*   hT   = (u16*)  alloc((size_t)V_ * H_ * 2);
  u16*   qkvT = (u16*)  alloc((size_t)QKVN * H_ * 2);
  u16*   oT   = (u16*)  alloc((size_t)H_ * H_ * 2);
  u16*   w1Tb = (u16*)  alloc((size_t)2 * H_ * FF_ * 2);  // double-buffered
  u16*   w2Tb = (u16*)  alloc((size_t)2 * FF_ * H_ * 2);  // double-buffered
  float* bqkv = (float*)alloc((size_t)L_ * QKVN * 4);
  (void)in_sizes; (void)n_in; (void)out_size; (void)ws_size;

  auto w1T = [&](int l) { return w1Tb + (size_t)(l & 1) * H_ * FF_; };
  auto w2T = [&](int l) { return w2Tb + (size_t)(l & 1) * FF_ * H_; };

  embed_concat_kernel<<<M_ + L_, 256, 0, stream>>>(x, tok, pos, h, hb,
                                                   bq, bk, bv, bqkv);
  // layer-0 weights: standalone transpose
  transpose_layer_k<<<768, 256, 0, stream>>>(
      Wq, Wk, Wv, Wo, W1, W2, qkvT, oT, w1T(0), w2T(0));

  for (int l = 0; l < L_; ++l) {
    // QKV: [2048,3072]
    gemm3<false, false, false, true><<<dim3(QKVN / 128, M_ / 128, 1), 256, 0, stream>>>(
        hb, qkvT, bqkv + (size_t)l * QKVN, nullptr, qkv, nullptr, QKVN, H_, H_);
    attn_kernel<<<dim3(T_ / 128, MB_ * NH_), 512, 0, stream>>>(qkv, ob_);
    // O-proj: split-K x4 -> 512 blocks, bf16 partials
    gemm3<true, false, false, false><<<dim3(H_ / 128, M_ / 128, 4), 256, 0, stream>>>(
        ob_, oT, nullptr, nullptr, nullptr, Pb, H_, H_, H_ / 4);
    ln2_kernel<<<M_, 256, 0, stream>>>(Pb, 4, bo + l * H_, g1 + l * H_, be1 + l * H_,
                                       nullptr, nullptr, h, hb);
    // W1 + GELU, fused with next-layer (or head) transpose
    if (l + 1 < L_) {
      int nl = l + 1;
      gemmW1_fused<<<512 + 768, 256, 0, stream>>>(
          hb, w1T(l), b1 + (size_t)l * FF_, m1,
          Wq + (size_t)nl * H_ * H_, Wk + (size_t)nl * H_ * H_,
          Wv + (size_t)nl * H_ * H_, Wo + (size_t)nl * H_ * H_,
          W1 + (size_t)nl * H_ * FF_, W2 + (size_t)nl * FF_ * H_,
          qkvT, oT, w1T(nl), w2T(nl), nullptr, nullptr);
    } else {
      gemmW1_fused<<<512 + 512, 256, 0, stream>>>(
          hb, w1T(l), b1 + (size_t)l * FF_, m1,
          nullptr, nullptr, nullptr, nullptr, nullptr, nullptr,
          nullptr, nullptr, nullptr, nullptr, hW, hT);
    }
    // W2: split-K x4 -> bf16 partials
    gemm3<true, false, false, false><<<dim3(H_ / 128, M_ / 128, 4), 256, 0, stream>>>(
        m1, w2T(l), nullptr, nullptr, nullptr, Pb, H_, FF_, FF_ / 4);
    if (l + 1 < L_) {
      ln2_kernel<<<M_, 256, 0, stream>>>(Pb, 4, b2 + l * H_, g2 + l * H_, be2 + l * H_,
                                         nullptr, nullptr, h, hb);
    } else {
      ln2_kernel<<<M_, 256, 0, stream>>>(Pb, 4, b2 + l * H_, g2 + l * H_, be2 + l * H_,
                                         gf, bef, h, hb);
    }
  }

  gemm3<false, false, true, false><<<dim3(V_ / 128, M_ / 128, 1), 256, 0, stream>>>(
      hb, hT, hbias, out, nullptr, nullptr, V_, H_, H_);
}